// Round 2
// baseline (119.532 us; speedup 1.0000x reference)
//
#include <hip/hip_runtime.h>

#define OUT_UNITS 128
#define BLOCK 64  // one wave per output row; lane handles 2 output cols (float2)

__global__ __launch_bounds__(BLOCK)
void spmm_row_wave(const float* __restrict__ vals,
                   const float* __restrict__ w,
                   const int* __restrict__ rows,
                   const int* __restrict__ cols,
                   float* __restrict__ out,
                   int nnz) {
    const int r = blockIdx.x;

    // lower_bound(rows, r) -> start ; lower_bound(rows, r+1) -> end
    // Wave-uniform: every lane runs the identical search (broadcast loads).
    int lo = 0, hi = nnz;
    while (lo < hi) {
        int mid = (lo + hi) >> 1;
        if (rows[mid] < r) lo = mid + 1; else hi = mid;
    }
    const int start = lo;
    hi = nnz;
    while (lo < hi) {
        int mid = (lo + hi) >> 1;
        if (rows[mid] < r + 1) lo = mid + 1; else hi = mid;
    }
    const int end = lo;

    const int lane = threadIdx.x;
    const float2* __restrict__ w2 = (const float2*)w;  // w row c: w2[c*64 + lane]

    float2 acc = make_float2(0.f, 0.f);

    int k = start;
    // 4-deep unroll for ILP: issue all col/val loads, then all w gathers.
    for (; k + 4 <= end; k += 4) {
        int   c0 = cols[k + 0], c1 = cols[k + 1];
        int   c2 = cols[k + 2], c3 = cols[k + 3];
        float v0 = vals[k + 0], v1 = vals[k + 1];
        float v2 = vals[k + 2], v3 = vals[k + 3];
        float2 w0  = w2[(size_t)c0 * (OUT_UNITS / 2) + lane];
        float2 w1  = w2[(size_t)c1 * (OUT_UNITS / 2) + lane];
        float2 w2v = w2[(size_t)c2 * (OUT_UNITS / 2) + lane];
        float2 w3v = w2[(size_t)c3 * (OUT_UNITS / 2) + lane];
        acc.x = fmaf(v0, w0.x, acc.x);  acc.y = fmaf(v0, w0.y, acc.y);
        acc.x = fmaf(v1, w1.x, acc.x);  acc.y = fmaf(v1, w1.y, acc.y);
        acc.x = fmaf(v2, w2v.x, acc.x); acc.y = fmaf(v2, w2v.y, acc.y);
        acc.x = fmaf(v3, w3v.x, acc.x); acc.y = fmaf(v3, w3v.y, acc.y);
    }
    for (; k < end; ++k) {
        int   c = cols[k];
        float v = vals[k];
        float2 wv = w2[(size_t)c * (OUT_UNITS / 2) + lane];
        acc.x = fmaf(v, wv.x, acc.x);
        acc.y = fmaf(v, wv.y, acc.y);
    }

    ((float2*)(out + (size_t)r * OUT_UNITS))[lane] = acc;
}

extern "C" void kernel_launch(void* const* d_in, const int* in_sizes, int n_in,
                              void* d_out, int out_size, void* d_ws, size_t ws_size,
                              hipStream_t stream) {
    const float* vals = (const float*)d_in[0];
    const float* w    = (const float*)d_in[1];
    const int*   rows = (const int*)d_in[2];
    const int*   cols = (const int*)d_in[3];
    float* out = (float*)d_out;

    const int nnz    = in_sizes[0];
    const int n_rows = out_size / OUT_UNITS;  // 16384

    spmm_row_wave<<<n_rows, BLOCK, 0, stream>>>(vals, w, rows, cols, out, nnz);
}

// Round 3
// 110.981 us; speedup vs baseline: 1.0771x; 1.0771x over previous
//
#include <hip/hip_runtime.h>

#define OUT_UNITS 128

// ---------------- Kernel 1: CSR row pointers from sorted COO rows ------------
// row_start[r] = first k with rows[k] >= r ; row_start[n_rows] = nnz.
// Every entry 0..n_rows is written exactly once (d_ws is poisoned each call).
__global__ void build_row_starts(const int* __restrict__ rows,
                                 int* __restrict__ row_start,
                                 int nnz, int n_rows) {
    int k = blockIdx.x * blockDim.x + threadIdx.x;
    if (k >= nnz) return;
    int cur = rows[k];
    if (k == 0) {
        for (int r = 0; r <= cur; ++r) row_start[r] = 0;
    } else {
        int prev = rows[k - 1];
        for (int r = prev + 1; r <= cur; ++r) row_start[r] = k;
    }
    if (k == nnz - 1) {
        for (int r = cur + 1; r <= n_rows; ++r) row_start[r] = nnz;
    }
}

// ---------------- Kernel 2: one wave per output row --------------------------
// Per 32-nnz chunk: lanes 0-31 load cols/vals coalesced once; v_readlane
// broadcasts (c,v) to SGPRs; the 32 w-row gathers are mutually independent
// (SGPR base + lane*8 offset) so the compiler keeps many in flight.
__global__ __launch_bounds__(64)
void spmm_row_wave(const float* __restrict__ vals,
                   const float* __restrict__ w,
                   const int* __restrict__ cols,
                   const int* __restrict__ row_start,
                   float* __restrict__ out) {
    const int r     = blockIdx.x;
    const int start = row_start[r];
    const int end   = row_start[r + 1];
    const int lane  = threadIdx.x;
    const float2* __restrict__ w2 = (const float2*)w;  // w row c: w2[c*64 + lane]

    float2 acc = make_float2(0.f, 0.f);

    int k = start;
    for (; k + 32 <= end; k += 32) {
        int c_l = 0; float v_l = 0.f;
        if (lane < 32) { c_l = cols[k + lane]; v_l = vals[k + lane]; }
#pragma unroll
        for (int j = 0; j < 32; ++j) {
            int   c = __builtin_amdgcn_readlane(c_l, j);
            float v = __uint_as_float(__builtin_amdgcn_readlane(__float_as_uint(v_l), j));
            float2 wv = w2[(size_t)c * (OUT_UNITS / 2) + lane];
            acc.x = fmaf(v, wv.x, acc.x);
            acc.y = fmaf(v, wv.y, acc.y);
        }
    }
    const int rem = end - k;
    if (rem > 0) {
        int c_l = 0; float v_l = 0.f;
        if (lane < rem) { c_l = cols[k + lane]; v_l = vals[k + lane]; }
        for (int j = 0; j < rem; ++j) {  // j wave-uniform -> readlane is scalar
            int   c = __builtin_amdgcn_readlane(c_l, j);
            float v = __uint_as_float(__builtin_amdgcn_readlane(__float_as_uint(v_l), j));
            float2 wv = w2[(size_t)c * (OUT_UNITS / 2) + lane];
            acc.x = fmaf(v, wv.x, acc.x);
            acc.y = fmaf(v, wv.y, acc.y);
        }
    }

    ((float2*)(out + (size_t)r * OUT_UNITS))[lane] = acc;
}

extern "C" void kernel_launch(void* const* d_in, const int* in_sizes, int n_in,
                              void* d_out, int out_size, void* d_ws, size_t ws_size,
                              hipStream_t stream) {
    const float* vals = (const float*)d_in[0];
    const float* w    = (const float*)d_in[1];
    const int*   rows = (const int*)d_in[2];
    const int*   cols = (const int*)d_in[3];
    float* out = (float*)d_out;

    const int nnz    = in_sizes[0];
    const int n_rows = out_size / OUT_UNITS;  // 16384

    int* row_start = (int*)d_ws;  // (n_rows + 1) ints

    build_row_starts<<<(nnz + 255) / 256, 256, 0, stream>>>(rows, row_start, nnz, n_rows);
    spmm_row_wave<<<n_rows, 64, 0, stream>>>(vals, w, cols, row_start, out);
}

// Round 4
// 106.644 us; speedup vs baseline: 1.1208x; 1.0407x over previous
//
#include <hip/hip_runtime.h>

#define OUT_UNITS 128

// ---------------- Kernel 1: CSR row pointers from sorted COO rows ------------
__global__ void build_row_starts(const int* __restrict__ rows,
                                 int* __restrict__ row_start,
                                 int nnz, int n_rows) {
    int k = blockIdx.x * blockDim.x + threadIdx.x;
    if (k >= nnz) return;
    int cur = rows[k];
    if (k == 0) {
        for (int r = 0; r <= cur; ++r) row_start[r] = 0;
    } else {
        int prev = rows[k - 1];
        for (int r = prev + 1; r <= cur; ++r) row_start[r] = k;
    }
    if (k == nnz - 1) {
        for (int r = cur + 1; r <= n_rows; ++r) row_start[r] = nnz;
    }
}

__device__ __forceinline__ float bc_f(float v, int j) {
    return __uint_as_float(__builtin_amdgcn_readlane(__float_as_uint(v), j));
}

// ---------------- Kernel 2: 4 waves/block, one row per wave ------------------
// Per 64-nnz chunk: all 64 lanes load cols/vals coalesced once. Halves of 32
// lanes each handle one nnz of a pair via float4 (16B) gathers -> one wave
// instruction moves 1KB covering 2 nnz. Cross-half shfl_xor(32) reduce at end.
__global__ __launch_bounds__(256)
void spmm_row_wave(const float* __restrict__ vals,
                   const float* __restrict__ w,
                   const int* __restrict__ cols,
                   const int* __restrict__ row_start,
                   float* __restrict__ out,
                   int n_rows) {
    const int wave = threadIdx.x >> 6;
    const int r    = blockIdx.x * 4 + wave;
    if (r >= n_rows) return;

    const int start = row_start[r];
    const int end   = row_start[r + 1];
    const int lane  = threadIdx.x & 63;
    const int half  = lane >> 5;       // 0 or 1: which nnz of the pair
    const int sub   = lane & 31;       // 32 lanes x float4 = 128 floats = w row
    const float4* __restrict__ w4 = (const float4*)w;  // row c: w4[c*32 + sub]

    float4 acc = make_float4(0.f, 0.f, 0.f, 0.f);

    int k = start;
    for (; k + 64 <= end; k += 64) {
        int   c_l = cols[k + lane];
        float v_l = vals[k + lane];
#pragma unroll
        for (int j = 0; j < 32; ++j) {
            int   c0 = __builtin_amdgcn_readlane(c_l, 2 * j);
            int   c1 = __builtin_amdgcn_readlane(c_l, 2 * j + 1);
            float v0 = bc_f(v_l, 2 * j);
            float v1 = bc_f(v_l, 2 * j + 1);
            int   c  = half ? c1 : c0;
            float v  = half ? v1 : v0;
            float4 wv = w4[(size_t)c * 32 + sub];
            acc.x = fmaf(v, wv.x, acc.x);
            acc.y = fmaf(v, wv.y, acc.y);
            acc.z = fmaf(v, wv.z, acc.z);
            acc.w = fmaf(v, wv.w, acc.w);
        }
    }

    const int rem = end - k;
    if (rem > 0) {
        // padded lanes: valid col (start), zero value -> contribute nothing
        int   c_l = (lane < rem) ? cols[k + lane] : cols[start];
        float v_l = (lane < rem) ? vals[k + lane] : 0.f;
        const int npair = (rem + 1) >> 1;
        for (int j = 0; j < npair; ++j) {  // j wave-uniform
            int   c0 = __builtin_amdgcn_readlane(c_l, 2 * j);
            int   c1 = __builtin_amdgcn_readlane(c_l, 2 * j + 1);
            float v0 = bc_f(v_l, 2 * j);
            float v1 = bc_f(v_l, 2 * j + 1);
            int   c  = half ? c1 : c0;
            float v  = half ? v1 : v0;
            float4 wv = w4[(size_t)c * 32 + sub];
            acc.x = fmaf(v, wv.x, acc.x);
            acc.y = fmaf(v, wv.y, acc.y);
            acc.z = fmaf(v, wv.z, acc.z);
            acc.w = fmaf(v, wv.w, acc.w);
        }
    }

    // combine the two halves (each summed a disjoint subset of nnz)
    acc.x += __shfl_xor(acc.x, 32);
    acc.y += __shfl_xor(acc.y, 32);
    acc.z += __shfl_xor(acc.z, 32);
    acc.w += __shfl_xor(acc.w, 32);

    if (half == 0) {
        ((float4*)(out + (size_t)r * OUT_UNITS))[sub] = acc;
    }
}

extern "C" void kernel_launch(void* const* d_in, const int* in_sizes, int n_in,
                              void* d_out, int out_size, void* d_ws, size_t ws_size,
                              hipStream_t stream) {
    const float* vals = (const float*)d_in[0];
    const float* w    = (const float*)d_in[1];
    const int*   rows = (const int*)d_in[2];
    const int*   cols = (const int*)d_in[3];
    float* out = (float*)d_out;

    const int nnz    = in_sizes[0];
    const int n_rows = out_size / OUT_UNITS;  // 16384

    int* row_start = (int*)d_ws;  // (n_rows + 1) ints

    build_row_starts<<<(nnz + 255) / 256, 256, 0, stream>>>(rows, row_start, nnz, n_rows);
    spmm_row_wave<<<(n_rows + 3) / 4, 256, 0, stream>>>(vals, w, cols, row_start, out, n_rows);
}